// Round 1
// baseline (271.828 us; speedup 1.0000x reference)
//
#include <hip/hip_runtime.h>
#include <math.h>

#define EPSV 1e-12f

// -------- block reduce helpers assume blockDim.x == 256 (4 waves of 64) ----

// ---------------------------------------------------------------------------
// Kernel 1: segment-sum of features into per-class sums + label histogram.
// Grid decomposition: b in [0,B), channel-group cg in [0,C/CH), chunk ck.
// Each block: stage labels chunk in LDS, loop CH channels with float4 loads,
// accumulate into privatized LDS bins, flush once with global atomics.
// cg==0 blocks additionally histogram the labels chunk into counts.
// ---------------------------------------------------------------------------
template<int CHUNK, int CH>
__global__ __launch_bounds__(256) void segsum_kernel(
    const float* __restrict__ feat,     // [B,C,HW]
    const int*   __restrict__ labels,   // [B,HW]
    const int*   __restrict__ ign_p,    // scalar
    float*       __restrict__ sums,     // [K,C]
    unsigned int* __restrict__ counts,  // [K]
    int B, int C, int HW, int K)
{
    const int NCH = HW / CHUNK;          // chunks per image
    const int CG  = C / CH;              // channel groups
    int bid = blockIdx.x;
    int b  = bid / (CG * NCH);
    int r  = bid % (CG * NCH);
    int cg = r / NCH;
    int ck = r % NCH;
    const int ig = *ign_p;

    __shared__ int   slab[CHUNK];
    __shared__ float bins[CH * 152];     // stride 152 (K=150 padded)
    __shared__ unsigned int cbins[152];

    const int tid = threadIdx.x;
    for (int i = tid; i < CH * 152; i += 256) bins[i] = 0.f;
    if (cg == 0) for (int i = tid; i < K; i += 256) cbins[i] = 0u;

    const int* lp = labels + (size_t)b * HW + (size_t)ck * CHUNK;
    for (int i = tid; i < CHUNK; i += 256) {
        int l = lp[i];
        int v = (l == ig) ? 0 : l;
        slab[i] = ((unsigned)v < (unsigned)K) ? v : -1;  // drop out-of-range
    }
    __syncthreads();

    if (cg == 0) {
        for (int i = tid; i < CHUNK; i += 256) {
            int l = slab[i];
            if (l >= 0) atomicAdd(&cbins[l], 1u);
        }
    }

    for (int ch = 0; ch < CH; ++ch) {
        const float* fp = feat + ((size_t)(b * C + cg * CH + ch)) * HW
                               + (size_t)ck * CHUNK;
        const float4* f4 = reinterpret_cast<const float4*>(fp);
        float* bch = &bins[ch * 152];
        for (int i = tid; i < CHUNK / 4; i += 256) {
            float4 v = f4[i];
            int l0 = slab[4*i+0], l1 = slab[4*i+1];
            int l2 = slab[4*i+2], l3 = slab[4*i+3];
            if (l0 >= 0) atomicAdd(&bch[l0], v.x);
            if (l1 >= 0) atomicAdd(&bch[l1], v.y);
            if (l2 >= 0) atomicAdd(&bch[l2], v.z);
            if (l3 >= 0) atomicAdd(&bch[l3], v.w);
        }
    }
    __syncthreads();

    for (int i = tid; i < CH * K; i += 256) {
        int ch = i / K, lab = i - ch * K;
        float v = bins[ch * 152 + lab];
        if (v != 0.f)
            atomicAdd(&sums[(size_t)lab * C + (size_t)(cg * CH + ch)], v);
    }
    if (cg == 0) {
        for (int i = tid; i < K; i += 256) {
            unsigned v = cbins[i];
            if (v) atomicAdd(&counts[i], v);
        }
    }
}

// ---------------------------------------------------------------------------
// Kernel 2: per-valid-row loss. Block k: normalize prototype row k (256 thr),
// then 4 waves sweep text rows j (fused text-norm + dot + online logsumexp).
// Adds -logp[k][k] into loss_acc.
// ---------------------------------------------------------------------------
__global__ __launch_bounds__(256) void rowloss_kernel(
    const float* __restrict__ sums,       // [K,C]
    const unsigned int* __restrict__ counts,
    const float* __restrict__ text,       // [K,C]
    float* __restrict__ loss_acc,
    int K, int C)
{
    int k = blockIdx.x;
    unsigned cnt = counts[k];
    if (cnt == 0) return;

    __shared__ float ph_lds[256];
    __shared__ float red[8];
    __shared__ float wred[4 * 3];

    int tid  = threadIdx.x;
    int wid  = tid >> 6;
    int lane = tid & 63;

    float p = sums[(size_t)k * C + tid] / (float)cnt;  // C == 256 == blockDim
    float v = p * p;
    #pragma unroll
    for (int o = 32; o > 0; o >>= 1) v += __shfl_down(v, o);
    if (lane == 0) red[wid] = v;
    __syncthreads();
    if (tid == 0) {
        float s = red[0] + red[1] + red[2] + red[3];
        red[4] = 1.0f / fmaxf(sqrtf(s), EPSV);
    }
    __syncthreads();
    ph_lds[tid] = p * red[4];
    __syncthreads();

    float m = -INFINITY, s = 0.f, simkk = 0.f;
    for (int j = wid; j < K; j += 4) {
        if (counts[j] == 0) continue;
        const float* tp = text + (size_t)j * C;
        float d = 0.f, tsq = 0.f;
        for (int cc = lane; cc < C; cc += 64) {
            float t = tp[cc];
            d   = fmaf(ph_lds[cc], t, d);
            tsq = fmaf(t, t, tsq);
        }
        #pragma unroll
        for (int o = 32; o > 0; o >>= 1) {
            d   += __shfl_down(d, o);
            tsq += __shfl_down(tsq, o);
        }
        if (lane == 0) {
            float sim = d * (1.0f / fmaxf(sqrtf(tsq), EPSV)) * 10.0f; // /TEMP
            if (j == k) simkk = sim;
            if (sim > m) { s = s * expf(m - sim) + 1.f; m = sim; }
            else         { s += expf(sim - m); }
        }
    }
    if (lane == 0) { wred[wid*3+0] = m; wred[wid*3+1] = s; wred[wid*3+2] = simkk; }
    __syncthreads();
    if (tid == 0) {
        float M = fmaxf(fmaxf(wred[0], wred[3]), fmaxf(wred[6], wred[9]));
        float S = 0.f, skk = 0.f;
        #pragma unroll
        for (int w = 0; w < 4; ++w) {
            float mw = wred[w*3+0];
            float sw = wred[w*3+1];
            S += (mw == -INFINITY) ? 0.f : sw * expf(mw - M);
            skk += wred[w*3+2];   // only owning wave nonzero-contributes
        }
        float contrib = M + logf(S) - skk;   // -logp[k][k]
        atomicAdd(loss_acc, contrib);
    }
}

// ---------------------------------------------------------------------------
// Kernel 3: finalize — n_valid, divide, n_valid<=1 -> 0.
// ---------------------------------------------------------------------------
__global__ __launch_bounds__(256) void finalize_kernel(
    const unsigned int* __restrict__ counts,
    const float* __restrict__ loss_acc,
    float* __restrict__ out, int K)
{
    __shared__ float red[4];
    int tid = threadIdx.x, wid = tid >> 6, lane = tid & 63;
    float v = (tid < K && counts[tid] > 0u) ? 1.f : 0.f;
    #pragma unroll
    for (int o = 32; o > 0; o >>= 1) v += __shfl_down(v, o);
    if (lane == 0) red[wid] = v;
    __syncthreads();
    if (tid == 0) {
        float nv = red[0] + red[1] + red[2] + red[3];
        float loss = loss_acc[0] / fmaxf(nv, 1.f);
        out[0] = (nv > 1.f) ? loss : 0.f;
    }
}

extern "C" void kernel_launch(void* const* d_in, const int* in_sizes, int n_in,
                              void* d_out, int out_size, void* d_ws, size_t ws_size,
                              hipStream_t stream) {
    const float* feat  = (const float*)d_in[0];
    const int*   labels = (const int*)d_in[1];
    const float* text  = (const float*)d_in[2];
    const int*   ign   = (const int*)d_in[3];

    const int B  = 8;
    const int N  = in_sizes[1];          // B*H*W = 131072
    const int HW = N / B;                // 16384
    const int C  = in_sizes[0] / N;      // 256
    const int K  = in_sizes[2] / C;      // 150

    // workspace layout (floats/uints)
    float*        sums     = (float*)d_ws;                 // K*C
    unsigned int* counts   = (unsigned int*)(sums + (size_t)K * C);
    float*        loss_acc = (float*)(counts + K);

    size_t zero_bytes = ((size_t)K * C + K + 1) * sizeof(float);
    hipMemsetAsync(d_ws, 0, zero_bytes, stream);

    constexpr int CHUNK = 4096;
    constexpr int CH    = 8;
    int grid = B * (C / CH) * (HW / CHUNK);   // 8*32*4 = 1024
    segsum_kernel<CHUNK, CH><<<grid, 256, 0, stream>>>(
        feat, labels, ign, sums, counts, B, C, HW, K);

    rowloss_kernel<<<K, 256, 0, stream>>>(sums, counts, text, loss_acc, K, C);

    finalize_kernel<<<1, 256, 0, stream>>>(counts, loss_acc, (float*)d_out, K);
}

// Round 2
// 251.743 us; speedup vs baseline: 1.0798x; 1.0798x over previous
//
#include <hip/hip_runtime.h>
#include <math.h>

#define EPSV 1e-12f

// ---------------------------------------------------------------------------
// Kernel A: label histogram -> counts[K].
// ---------------------------------------------------------------------------
__global__ __launch_bounds__(256) void counts_kernel(
    const int* __restrict__ labels, const int* __restrict__ ign_p,
    unsigned int* __restrict__ counts, int N, int K)
{
    __shared__ unsigned int cbins[160];
    const int tid = threadIdx.x;
    for (int i = tid; i < 160; i += 256) cbins[i] = 0u;
    __syncthreads();
    const int ig = *ign_p;
    const int4* l4 = reinterpret_cast<const int4*>(labels);
    const int n4 = N / 4;
    for (int i = blockIdx.x * 256 + tid; i < n4; i += gridDim.x * 256) {
        int4 v = l4[i];
        int a0 = (v.x == ig) ? 0 : v.x;
        int a1 = (v.y == ig) ? 0 : v.y;
        int a2 = (v.z == ig) ? 0 : v.z;
        int a3 = (v.w == ig) ? 0 : v.w;
        if ((unsigned)a0 < (unsigned)K) atomicAdd(&cbins[a0], 1u);
        if ((unsigned)a1 < (unsigned)K) atomicAdd(&cbins[a1], 1u);
        if ((unsigned)a2 < (unsigned)K) atomicAdd(&cbins[a2], 1u);
        if ((unsigned)a3 < (unsigned)K) atomicAdd(&cbins[a3], 1u);
    }
    __syncthreads();
    for (int i = tid; i < K; i += 256)
        if (cbins[i]) atomicAdd(&counts[i], cbins[i]);
}

// ---------------------------------------------------------------------------
// Kernel B: segment-sum. One block = one (batch, channel, 4096-pixel chunk).
// Labels live in registers (4x int4 per thread) -> no LDS staging, no sync
// before atomics, 8 independent global loads in flight per wave.
// LDS = one 160-float bin array (640 B) -> thread-capped occupancy (8 blk/CU).
// ---------------------------------------------------------------------------
template<int CHUNK>
__global__ __launch_bounds__(256) void segsum_kernel(
    const float* __restrict__ feat,     // [B,C,HW]
    const int*   __restrict__ labels,   // [B,HW]
    const int*   __restrict__ ign_p,
    float*       __restrict__ sums,     // [K,C]
    int B, int C, int HW, int K)
{
    constexpr int QPT = CHUNK / 4 / 256;   // float4-quads per thread (4)
    __shared__ float bins[160];

    const int NCH = HW / CHUNK;
    int bid = blockIdx.x;
    int c   = bid % C;                     // consecutive blocks share labels
    int t2  = bid / C;
    int ck  = t2 % NCH;
    int b   = t2 / NCH;
    const int ig  = *ign_p;
    const int tid = threadIdx.x;

    for (int i = tid; i < 160; i += 256) bins[i] = 0.f;
    __syncthreads();

    const int4*   l4 = reinterpret_cast<const int4*>(
                         labels + (size_t)b * HW + (size_t)ck * CHUNK);
    const float4* f4 = reinterpret_cast<const float4*>(
                         feat + ((size_t)b * C + c) * HW + (size_t)ck * CHUNK);

    int4   lv[QPT];
    float4 fv[QPT];
    #pragma unroll
    for (int j = 0; j < QPT; ++j) lv[j] = l4[tid + 256 * j];
    #pragma unroll
    for (int j = 0; j < QPT; ++j) fv[j] = f4[tid + 256 * j];

    #pragma unroll
    for (int j = 0; j < QPT; ++j) {
        int a0 = (lv[j].x == ig) ? 0 : lv[j].x;
        int a1 = (lv[j].y == ig) ? 0 : lv[j].y;
        int a2 = (lv[j].z == ig) ? 0 : lv[j].z;
        int a3 = (lv[j].w == ig) ? 0 : lv[j].w;
        if ((unsigned)a0 < (unsigned)K) atomicAdd(&bins[a0], fv[j].x);
        if ((unsigned)a1 < (unsigned)K) atomicAdd(&bins[a1], fv[j].y);
        if ((unsigned)a2 < (unsigned)K) atomicAdd(&bins[a2], fv[j].z);
        if ((unsigned)a3 < (unsigned)K) atomicAdd(&bins[a3], fv[j].w);
    }
    __syncthreads();

    for (int i = tid; i < K; i += 256)
        atomicAdd(&sums[(size_t)i * C + c], bins[i]);
}

// ---------------------------------------------------------------------------
// Kernel C: per-valid-row loss. Block k: normalize prototype row k, then
// 4 waves sweep text rows (fused text-norm + dot + online logsumexp).
// ---------------------------------------------------------------------------
__global__ __launch_bounds__(256) void rowloss_kernel(
    const float* __restrict__ sums,       // [K,C]
    const unsigned int* __restrict__ counts,
    const float* __restrict__ text,       // [K,C]
    float* __restrict__ loss_acc,
    int K, int C)
{
    int k = blockIdx.x;
    unsigned cnt = counts[k];
    if (cnt == 0) return;

    __shared__ float ph_lds[256];
    __shared__ float red[8];
    __shared__ float wred[4 * 3];

    int tid  = threadIdx.x;
    int wid  = tid >> 6;
    int lane = tid & 63;

    float p = sums[(size_t)k * C + tid] / (float)cnt;  // C == 256 == blockDim
    float v = p * p;
    #pragma unroll
    for (int o = 32; o > 0; o >>= 1) v += __shfl_down(v, o);
    if (lane == 0) red[wid] = v;
    __syncthreads();
    if (tid == 0) {
        float s = red[0] + red[1] + red[2] + red[3];
        red[4] = 1.0f / fmaxf(sqrtf(s), EPSV);
    }
    __syncthreads();
    ph_lds[tid] = p * red[4];
    __syncthreads();

    float m = -INFINITY, s = 0.f, simkk = 0.f;
    for (int j = wid; j < K; j += 4) {
        if (counts[j] == 0) continue;
        const float* tp = text + (size_t)j * C;
        float d = 0.f, tsq = 0.f;
        for (int cc = lane; cc < C; cc += 64) {
            float t = tp[cc];
            d   = fmaf(ph_lds[cc], t, d);
            tsq = fmaf(t, t, tsq);
        }
        #pragma unroll
        for (int o = 32; o > 0; o >>= 1) {
            d   += __shfl_down(d, o);
            tsq += __shfl_down(tsq, o);
        }
        if (lane == 0) {
            float sim = d * (1.0f / fmaxf(sqrtf(tsq), EPSV)) * 10.0f; // /TEMP
            if (j == k) simkk = sim;
            if (sim > m) { s = s * expf(m - sim) + 1.f; m = sim; }
            else         { s += expf(sim - m); }
        }
    }
    if (lane == 0) { wred[wid*3+0] = m; wred[wid*3+1] = s; wred[wid*3+2] = simkk; }
    __syncthreads();
    if (tid == 0) {
        float M = fmaxf(fmaxf(wred[0], wred[3]), fmaxf(wred[6], wred[9]));
        float S = 0.f, skk = 0.f;
        #pragma unroll
        for (int w = 0; w < 4; ++w) {
            float mw = wred[w*3+0];
            float sw = wred[w*3+1];
            S += (mw == -INFINITY) ? 0.f : sw * expf(mw - M);
            skk += wred[w*3+2];
        }
        float contrib = M + logf(S) - skk;   // -logp[k][k]
        atomicAdd(loss_acc, contrib);
    }
}

// ---------------------------------------------------------------------------
// Kernel D: finalize.
// ---------------------------------------------------------------------------
__global__ __launch_bounds__(256) void finalize_kernel(
    const unsigned int* __restrict__ counts,
    const float* __restrict__ loss_acc,
    float* __restrict__ out, int K)
{
    __shared__ float red[4];
    int tid = threadIdx.x, wid = tid >> 6, lane = tid & 63;
    float v = (tid < K && counts[tid] > 0u) ? 1.f : 0.f;
    #pragma unroll
    for (int o = 32; o > 0; o >>= 1) v += __shfl_down(v, o);
    if (lane == 0) red[wid] = v;
    __syncthreads();
    if (tid == 0) {
        float nv = red[0] + red[1] + red[2] + red[3];
        float loss = loss_acc[0] / fmaxf(nv, 1.f);
        out[0] = (nv > 1.f) ? loss : 0.f;
    }
}

extern "C" void kernel_launch(void* const* d_in, const int* in_sizes, int n_in,
                              void* d_out, int out_size, void* d_ws, size_t ws_size,
                              hipStream_t stream) {
    const float* feat   = (const float*)d_in[0];
    const int*   labels = (const int*)d_in[1];
    const float* text   = (const float*)d_in[2];
    const int*   ign    = (const int*)d_in[3];

    const int B  = 8;
    const int N  = in_sizes[1];          // B*H*W = 131072
    const int HW = N / B;                // 16384
    const int C  = in_sizes[0] / N;      // 256
    const int K  = in_sizes[2] / C;      // 150

    float*        sums     = (float*)d_ws;                 // K*C
    unsigned int* counts   = (unsigned int*)(sums + (size_t)K * C);
    float*        loss_acc = (float*)(counts + K);

    size_t zero_bytes = ((size_t)K * C + K + 1) * sizeof(float);
    hipMemsetAsync(d_ws, 0, zero_bytes, stream);

    counts_kernel<<<256, 256, 0, stream>>>(labels, ign, counts, N, K);

    constexpr int CHUNK = 4096;
    int grid = B * C * (HW / CHUNK);     // 8*256*4 = 8192
    segsum_kernel<CHUNK><<<grid, 256, 0, stream>>>(
        feat, labels, ign, sums, B, C, HW, K);

    rowloss_kernel<<<K, 256, 0, stream>>>(sums, counts, text, loss_acc, K, C);

    finalize_kernel<<<1, 256, 0, stream>>>(counts, loss_acc, (float*)d_out, K);
}